// Round 2
// baseline (1832.937 us; speedup 1.0000x reference)
//
#include <hip/hip_runtime.h>

typedef float F2 __attribute__((ext_vector_type(2)));

#define NB 4
#define NC 17
#define T0 75000
#define NH 32
#define NK 8

// ---- pack k into low 3 mantissa bits so fmax/fmin trees carry the argindex ----
__device__ __forceinline__ float packK(float z, int k) {
    unsigned u = (__float_as_uint(z) & 0xFFFFFFF8u) | (unsigned)k;
    return __uint_as_float(u);
}

// per-position epilogue: packed argmax/argmin + LDS bin add + packed counter
// SHIFT: log2 bits per count field (2 -> 4-bit fields, 3 -> 8-bit fields)
template <int SHIFT>
__device__ __forceinline__ void epilogue(const float* z, bool valid,
                                         float* binsM, unsigned long long& cnt) {
    float p[8];
#pragma unroll
    for (int k = 0; k < 8; ++k) p[k] = packK(z[k], k);
    float a0 = fmaxf(p[0], p[1]), a1 = fmaxf(p[2], p[3]);
    float a2 = fmaxf(p[4], p[5]), a3 = fmaxf(p[6], p[7]);
    float best = fmaxf(fmaxf(a0, a1), fmaxf(a2, a3));
    float b0 = fminf(p[0], p[1]), b1 = fminf(p[2], p[3]);
    float b2 = fminf(p[4], p[5]), b3 = fminf(p[6], p[7]);
    float worst = fminf(fminf(b0, b1), fminf(b2, b3));
    if (valid) {
        int biK = __float_as_uint(best) & 7;
        int wiK = __float_as_uint(worst) & 7;
        atomicAdd(&binsM[biK << 8], best);     // ds_add_f32, lane-private slot
        cnt += 1ull << (wiK << SHIFT);
    }
}

// block-wide reduce of 16x256 bins -> 16 atomics
__device__ __forceinline__ void block_reduce_out(float* accLDS, int tid, int ga,
                                                 int b, int h, float* out) {
    __syncthreads();
    int bin = tid >> 4, i0 = tid & 15;
    float v = 0.f;
#pragma unroll
    for (int j = 0; j < 16; ++j) v += accLDS[(bin << 8) + i0 + (j << 4)];
    v += __shfl_xor(v, 1, 64);
    v += __shfl_xor(v, 2, 64);
    v += __shfl_xor(v, 4, 64);
    v += __shfl_xor(v, 8, 64);
    if (i0 == 0) {
        int k = bin & 7;
        int o = ga * 2 + (bin >> 3);           // 0..7 -> max sums, 8..15 -> min counts
        atomicAdd(&out[(size_t)b * 14336 + (o * NH + h) * NK + k], v);
    }
}

// ---------------- kernel A: di 0..5 (d = 1..32), LDS-tiled, pk-paired ----------------
constexpr int TS = 1024;
constexpr int A_TILES = 74;
constexpr int A_BLOCKS_PER_G = 128 * A_TILES;
constexpr int A_GROUPS = 12;
constexpr int A_TOTAL_BLOCKS = A_GROUPS * A_BLOCKS_PER_G;

__global__ __launch_bounds__(256) void kernA(const float* __restrict__ X,
                                             const float* __restrict__ Wt,
                                             const int* __restrict__ idx,
                                             float* __restrict__ out) {
    __shared__ float Sbuf[TS + 8 * 32 + 2];
    __shared__ float Dbuf[TS + 8 * 32];
    __shared__ float accLDS[16 * 256];

    const int tid = threadIdx.x;
    const int bid = blockIdx.x;
    const int ga = bid / A_BLOCKS_PER_G;
    const int rem = bid - ga * A_BLOCKS_PER_G;
    const int combo = rem / A_TILES;
    const int tile = rem - combo * A_TILES;
    const int di = ga >> 1, diff = ga & 1;
    const int d = 1 << di;
    const int T = T0 - diff;
    const int b = combo >> 5, h = combo & 31;
    const int t0 = tile * TS;
    const int span = TS + 8 * d;

    const int* ip = idx + (ga * NH + h) * 8;
    int offs[8];
#pragma unroll
    for (int i = 0; i < 8; ++i)
        offs[i] = __builtin_amdgcn_readfirstlane((b * NC + ip[i]) * T0);

#pragma unroll
    for (int k = 0; k < 16; ++k) accLDS[(k << 8) + tid] = 0.f;

    // stage S = 8-channel sum over [g0, g0+span], vectorized float2
    const int g0 = t0 - 4 * d;                 // even -> aligned b64 loads
    const int nst = span + 1;
    for (int e = tid * 2; e < nst; e += 512) {
        int u = g0 + e;
        F2 s = {0.f, 0.f};
        if (u >= 0 && u + 1 < T0) {
#pragma unroll
            for (int i = 0; i < 8; ++i) s += *(const F2*)(X + offs[i] + u);
        } else {
#pragma unroll
            for (int c = 0; c < 2; ++c) {
                int uc = u + c;
                float sc = 0.f;
                if (uc >= 0 && uc < T0) {
#pragma unroll
                    for (int i = 0; i < 8; ++i) sc += X[offs[i] + uc];
                }
                s[c] = sc;
            }
        }
        if (e + 1 <= span) *(F2*)(Sbuf + e) = s;
        else Sbuf[e] = s.x;
    }
    __syncthreads();
    const float* src = Sbuf;
    if (diff) {
        for (int ls = tid; ls < span; ls += 256) {
            int u = g0 + ls;
            Dbuf[ls] = (u >= 0 && u < T) ? (Sbuf[ls + 1] - Sbuf[ls]) : 0.f;
        }
        __syncthreads();
        src = Dbuf;
    }

    const float* wp = Wt + (ga * (NK * NH) + h * NK) * 9;
    float w[72];
#pragma unroll
    for (int i = 0; i < 72; ++i) w[i] = wp[i];  // uniform -> SGPRs

    float* binsM = accLDS + tid;
    unsigned long long cnt = 0;

#pragma unroll
    for (int it = 0; it < 2; ++it) {
        const int p = 2 * tid + it * 512;
        F2 z2[8];
#pragma unroll
        for (int k = 0; k < 8; ++k) z2[k] = (F2){0.f, 0.f};
#pragma unroll
        for (int j = 0; j < 9; ++j) {
            F2 g2 = {src[p + j * d], src[p + 1 + j * d]};
#pragma unroll
            for (int k = 0; k < 8; ++k) {
                F2 wv = {w[k * 9 + j], w[k * 9 + j]};
                z2[k] = __builtin_elementwise_fma(wv, g2, z2[k]);
            }
        }
        float zx[8], zy[8];
#pragma unroll
        for (int k = 0; k < 8; ++k) { zx[k] = z2[k].x; zy[k] = z2[k].y; }
        const int t = t0 + p;
        epilogue<2>(zx, t < T, binsM, cnt);
        epilogue<2>(zy, t + 1 < T, binsM, cnt);
    }

#pragma unroll
    for (int k = 0; k < 8; ++k)
        accLDS[((8 + k) << 8) + tid] = (float)((unsigned)(cnt >> (k * 4)) & 15u);

    block_reduce_out(accLDS, tid, ga, b, h, out);
}

// ---------------- kernel B: di 6..13 (d = 64..8192), chains, SEG=60 pairs ----------------
struct BG { int base, segs, di, diff; };
constexpr BG BGS[16] = {
    {0,       1280,  6, 0}, {163840,  1280,  6, 1},
    {327680,  1280,  7, 0}, {491520,  1280,  7, 1},
    {655360,  1280,  8, 0}, {819200,  1280,  8, 1},
    {983040,  1536,  9, 0}, {1179648, 1536,  9, 1},
    {1376256, 2048, 10, 0}, {1638400, 2048, 10, 1},
    {1900544, 2048, 11, 0}, {2162688, 2048, 11, 1},
    {2424832, 4096, 12, 0}, {2949120, 4096, 12, 1},
    {3473408, 8192, 13, 0}, {4521984, 8192, 13, 1},
};
constexpr int B_TOTAL = 5570560;
constexpr int B_BLOCKS = B_TOTAL / 256;        // 21760

__device__ __forceinline__ float gatherF(const float* __restrict__ X,
                                         const int* offs, int u, int T, int diffF) {
    float s = 0.f;
    if (u >= 0 && u < T) {
        if (diffF) {
            F2 acc = {0.f, 0.f};
#pragma unroll
            for (int i = 0; i < 8; ++i) {
                F2 t = {X[offs[i] + u], X[offs[i] + u + 1]};
                acc += t;
            }
            s = acc.y - acc.x;
        } else {
            float a0 = X[offs[0] + u], a1 = X[offs[1] + u];
            float a2 = X[offs[2] + u], a3 = X[offs[3] + u];
            float a4 = X[offs[4] + u], a5 = X[offs[5] + u];
            float a6 = X[offs[6] + u], a7 = X[offs[7] + u];
            s = ((a0 + a1) + (a2 + a3)) + ((a4 + a5) + (a6 + a7));
        }
    }
    return s;
}

__global__ __launch_bounds__(256) void kernB(const float* __restrict__ X,
                                             const float* __restrict__ Wt,
                                             const int* __restrict__ idx,
                                             float* __restrict__ out) {
    __shared__ float accLDS[16 * 256];
    const int tid = threadIdx.x;
    const int gtid = blockIdx.x * 256 + tid;

    int di = 6, diff = 0, r = 0, q0 = 0, combo = 0;
#pragma unroll
    for (int g = 0; g < 16; ++g) {
        const int base = BGS[g].base, segs = BGS[g].segs;
        if (gtid >= base && gtid < base + 128 * segs) {
            int wgi = gtid - base;
            int c = wgi / segs;                // compile-time magic div
            int s = wgi - c * segs;
            combo = c;
            q0 = (s >> BGS[g].di) * 60;
            r = s & ((1 << BGS[g].di) - 1);
            di = BGS[g].di; diff = BGS[g].diff;
        }
    }
    di    = __builtin_amdgcn_readfirstlane(di);
    diff  = __builtin_amdgcn_readfirstlane(diff);
    combo = __builtin_amdgcn_readfirstlane(combo);
    q0    = __builtin_amdgcn_readfirstlane(q0);

    const int d = 1 << di;
    const int T = T0 - diff;
    const int Q = (T + d - 1) >> di;
    const int b = combo >> 5, h = combo & 31;
    const int ga = di * 2 + diff;

    const int* ip = idx + (ga * NH + h) * 8;
    int offs[8];
#pragma unroll
    for (int i = 0; i < 8; ++i)
        offs[i] = __builtin_amdgcn_readfirstlane((b * NC + ip[i]) * T0);

    const float* wp = Wt + (ga * (NK * NH) + h * NK) * 9;
    float w[72];
#pragma unroll
    for (int i = 0; i < 72; ++i) w[i] = wp[i];

#pragma unroll
    for (int k = 0; k < 16; ++k) accLDS[(k << 8) + tid] = 0.f;
    float* binsM = accLDS + tid;
    unsigned long long cnt = 0;

    const int t0 = r + q0 * d;
    float buf[10];
    {
        int u = t0 - 4 * d;
#pragma unroll
        for (int m = 0; m < 10; ++m) { buf[m] = gatherF(X, offs, u, T, diff); u += d; }
    }
    int tl = t0 + 6 * d;
    int tpos = t0;
    const int d2 = d * 2;

    for (int outer = 0; outer < 6; ++outer) {
        if (q0 + outer * 10 >= Q) break;
#pragma unroll
        for (int pp = 0; pp < 5; ++pp) {
            F2 z2[8];
#pragma unroll
            for (int k = 0; k < 8; ++k) z2[k] = (F2){0.f, 0.f};
#pragma unroll
            for (int j = 0; j < 9; ++j) {
                F2 g2 = {buf[(2 * pp + j) % 10], buf[(2 * pp + 1 + j) % 10]};
#pragma unroll
                for (int k = 0; k < 8; ++k) {
                    F2 wv = {w[k * 9 + j], w[k * 9 + j]};
                    z2[k] = __builtin_elementwise_fma(wv, g2, z2[k]);
                }
            }
            float zx[8], zy[8];
#pragma unroll
            for (int k = 0; k < 8; ++k) { zx[k] = z2[k].x; zy[k] = z2[k].y; }
            epilogue<3>(zx, tpos < T, binsM, cnt);
            epilogue<3>(zy, tpos + d < T, binsM, cnt);
            tpos += d2;
            buf[(2 * pp) % 10]     = gatherF(X, offs, tl, T, diff);
            buf[(2 * pp + 1) % 10] = gatherF(X, offs, tl + d, T, diff);
            tl += d2;
        }
    }

#pragma unroll
    for (int k = 0; k < 8; ++k)
        accLDS[((8 + k) << 8) + tid] = (float)((unsigned)(cnt >> (k * 8)) & 255u);

    block_reduce_out(accLDS, tid, ga, b, h, out);
}

__global__ void zeroK(float* __restrict__ out, int n) {
    int i = blockIdx.x * 256 + threadIdx.x;
    if (i < n) out[i] = 0.f;
}

extern "C" void kernel_launch(void* const* d_in, const int* in_sizes, int n_in,
                              void* d_out, int out_size, void* d_ws, size_t ws_size,
                              hipStream_t stream) {
    const float* X  = (const float*)d_in[0];
    const float* Wt = (const float*)d_in[1];
    const int*  idx = (const int*)d_in[2];
    float* out = (float*)d_out;

    zeroK<<<(out_size + 255) / 256, 256, 0, stream>>>(out, out_size);
    kernA<<<A_TOTAL_BLOCKS, 256, 0, stream>>>(X, Wt, idx, out);
    kernB<<<B_BLOCKS, 256, 0, stream>>>(X, Wt, idx, out);
}

// Round 3
// 1769.600 us; speedup vs baseline: 1.0358x; 1.0358x over previous
//
#include <hip/hip_runtime.h>

typedef float F2 __attribute__((ext_vector_type(2)));

#define NB 4
#define NC 17
#define T0 75000
#define NH 32
#define NK 8

// pack k into low 3 mantissa bits so fmax/fmin trees carry the arg-index
__device__ __forceinline__ float packK(float z, int k) {
    unsigned u = (__float_as_uint(z) & 0xFFFFFFF8u) | (unsigned)k;
    return __uint_as_float(u);
}
__device__ __forceinline__ float max8(const float* p) {
    return fmaxf(fmaxf(fmaxf(p[0], p[1]), fmaxf(p[2], p[3])),
                 fmaxf(fmaxf(p[4], p[5]), fmaxf(p[6], p[7])));
}
__device__ __forceinline__ float min8(const float* p) {
    return fminf(fminf(fminf(p[0], p[1]), fminf(p[2], p[3])),
                 fminf(fminf(p[4], p[5]), fminf(p[6], p[7])));
}

// block-wide reduce of 16x256 bins -> 16 atomics
__device__ __forceinline__ void block_reduce_out(float* accLDS, int tid, int ga,
                                                 int b, int h, float* out) {
    __syncthreads();
    int bin = tid >> 4, i0 = tid & 15;
    float v = 0.f;
#pragma unroll
    for (int j = 0; j < 16; ++j) v += accLDS[(bin << 8) + i0 + (j << 4)];
    v += __shfl_xor(v, 1, 64);
    v += __shfl_xor(v, 2, 64);
    v += __shfl_xor(v, 4, 64);
    v += __shfl_xor(v, 8, 64);
    if (i0 == 0) {
        int k = bin & 7;
        int o = ga * 2 + (bin >> 3);
        atomicAdd(&out[(size_t)b * 14336 + (o * NH + h) * NK + k], v);
    }
}

// k-paired weight load: w2[j*4+kp] = {W[2kp][j], W[2kp+1][j]}
__device__ __forceinline__ void load_w2(const float* __restrict__ wp, F2* w2) {
#pragma unroll
    for (int j = 0; j < 9; ++j)
#pragma unroll
        for (int kp = 0; kp < 4; ++kp)
            w2[j * 4 + kp] = (F2){wp[(2 * kp) * 9 + j], wp[(2 * kp + 1) * 9 + j]};
}

// ---------------- kernel A: di 0..5 (d = 1..32), LDS-tiled ----------------
constexpr int TS = 1024;
constexpr int A_TILES = 74;
constexpr int A_BLOCKS_PER_G = 128 * A_TILES;
constexpr int A_GROUPS = 12;
constexpr int A_TOTAL_BLOCKS = A_GROUPS * A_BLOCKS_PER_G;

__global__ __launch_bounds__(256, 4) void kernA(const float* __restrict__ X,
                                                const float* __restrict__ Wt,
                                                const int* __restrict__ idx,
                                                float* __restrict__ out) {
    __shared__ float Sbuf[TS + 8 * 32 + 4];
    __shared__ float Dbuf[TS + 8 * 32];
    __shared__ float accLDS[16 * 256];

    const int tid = threadIdx.x;
    const int bid = blockIdx.x;
    const int ga = bid / A_BLOCKS_PER_G;
    const int rem = bid - ga * A_BLOCKS_PER_G;
    const int combo = rem / A_TILES;
    const int tile = rem - combo * A_TILES;
    const int di = ga >> 1, diff = ga & 1;
    const int d = 1 << di;
    const int T = T0 - diff;
    const int b = combo >> 5, h = combo & 31;
    const int t0 = tile * TS;
    const int span = TS + 8 * d;

    const int* ip = idx + (ga * NH + h) * 8;
    int offs[8];
#pragma unroll
    for (int i = 0; i < 8; ++i)
        offs[i] = __builtin_amdgcn_readfirstlane((b * NC + ip[i]) * T0);

#pragma unroll
    for (int k = 0; k < 16; ++k) accLDS[(k << 8) + tid] = 0.f;

    // stage S = 8-channel sum over [g0, g0+span]
    const int g0 = t0 - 4 * d;                 // even
    const int nst = span + 1;
    for (int e = tid * 2; e < nst; e += 512) {
        int u = g0 + e;
        F2 s = {0.f, 0.f};
        if (u >= 0 && u + 1 < T0) {
#pragma unroll
            for (int i = 0; i < 8; ++i) s += *(const F2*)(X + offs[i] + u);
        } else {
#pragma unroll
            for (int c = 0; c < 2; ++c) {
                int uc = u + c;
                float sc = 0.f;
                if (uc >= 0 && uc < T0) {
#pragma unroll
                    for (int i = 0; i < 8; ++i) sc += X[offs[i] + uc];
                }
                s[c] = sc;
            }
        }
        if (e + 1 <= span) *(F2*)(Sbuf + e) = s;
        else Sbuf[e] = s.x;
    }
    __syncthreads();
    const float* src = Sbuf;
    if (diff) {
        for (int ls = tid; ls < span; ls += 256) {
            int u = g0 + ls;
            Dbuf[ls] = (u >= 0 && u < T) ? (Sbuf[ls + 1] - Sbuf[ls]) : 0.f;
        }
        __syncthreads();
        src = Dbuf;
    }

    F2 w2[36];
    load_w2(Wt + (ga * (NK * NH) + h * NK) * 9, w2);

    float bestv[4], worstv[4];
    int validm = 0;

#pragma unroll
    for (int it = 0; it < 4; ++it) {
        const int p = tid + it * 256;
        F2 z2[4];
#pragma unroll
        for (int kp = 0; kp < 4; ++kp) z2[kp] = (F2){0.f, 0.f};
#pragma unroll
        for (int j = 0; j < 9; ++j) {
            float g = src[p + j * d];
            F2 g2 = {g, g};
#pragma unroll
            for (int kp = 0; kp < 4; ++kp)
                z2[kp] = __builtin_elementwise_fma(w2[j * 4 + kp], g2, z2[kp]);
        }
        float pz[8];
#pragma unroll
        for (int kp = 0; kp < 4; ++kp) {
            pz[2 * kp]     = packK(z2[kp].x, 2 * kp);
            pz[2 * kp + 1] = packK(z2[kp].y, 2 * kp + 1);
        }
        bestv[it]  = max8(pz);
        worstv[it] = min8(pz);
        if (t0 + p < T) validm |= (1 << it);
    }

    // deferred binning (no LDS atomics inside the conv loop)
    float* binsM = accLDS + tid;
    unsigned long long cnt = 0;
#pragma unroll
    for (int it = 0; it < 4; ++it) {
        if (validm & (1 << it)) {
            int biK = __float_as_uint(bestv[it]) & 7;
            int wiK = __float_as_uint(worstv[it]) & 7;
            atomicAdd(&binsM[biK << 8], bestv[it]);
            cnt += 1ull << (wiK << 2);
        }
    }
#pragma unroll
    for (int k = 0; k < 8; ++k)
        accLDS[((8 + k) << 8) + tid] = (float)((unsigned)(cnt >> (k * 4)) & 15u);

    block_reduce_out(accLDS, tid, ga, b, h, out);
}

// ---------------- kernel B: di 6..13 (d = 64..8192), register chains ----------------
struct BG { int base, segs, di, diff; };
constexpr BG BGS[16] = {
    {0,       1280,  6, 0}, {163840,  1280,  6, 1},
    {327680,  1280,  7, 0}, {491520,  1280,  7, 1},
    {655360,  1280,  8, 0}, {819200,  1280,  8, 1},
    {983040,  1536,  9, 0}, {1179648, 1536,  9, 1},
    {1376256, 2048, 10, 0}, {1638400, 2048, 10, 1},
    {1900544, 2048, 11, 0}, {2162688, 2048, 11, 1},
    {2424832, 4096, 12, 0}, {2949120, 4096, 12, 1},
    {3473408, 8192, 13, 0}, {4521984, 8192, 13, 1},
};
constexpr int B_TOTAL = 5570560;
constexpr int B_BLOCKS = B_TOTAL / 256;        // 21760

__device__ __forceinline__ float gatherF(const float* __restrict__ X,
                                         const int* offs, int u, int T, int diffF) {
    float s = 0.f;
    if (u >= 0 && u < T) {
        if (diffF) {
            F2 acc = {0.f, 0.f};
#pragma unroll
            for (int i = 0; i < 8; ++i) {
                F2 t = {X[offs[i] + u], X[offs[i] + u + 1]};
                acc += t;
            }
            s = acc.y - acc.x;
        } else {
            float a0 = X[offs[0] + u], a1 = X[offs[1] + u];
            float a2 = X[offs[2] + u], a3 = X[offs[3] + u];
            float a4 = X[offs[4] + u], a5 = X[offs[5] + u];
            float a6 = X[offs[6] + u], a7 = X[offs[7] + u];
            s = ((a0 + a1) + (a2 + a3)) + ((a4 + a5) + (a6 + a7));
        }
    }
    return s;
}

__global__ __launch_bounds__(256, 4) void kernB(const float* __restrict__ X,
                                                const float* __restrict__ Wt,
                                                const int* __restrict__ idx,
                                                float* __restrict__ out) {
    __shared__ float accLDS[16 * 256];
    const int tid = threadIdx.x;
    const int gtid = blockIdx.x * 256 + tid;

    int di = 6, diff = 0, r = 0, q0 = 0, combo = 0;
#pragma unroll
    for (int g = 0; g < 16; ++g) {
        const int base = BGS[g].base, segs = BGS[g].segs;
        if (gtid >= base && gtid < base + 128 * segs) {
            int wgi = gtid - base;
            int c = wgi / segs;                // compile-time magic div
            int s = wgi - c * segs;
            combo = c;
            q0 = (s >> BGS[g].di) * 60;
            r = s & ((1 << BGS[g].di) - 1);
            di = BGS[g].di; diff = BGS[g].diff;
        }
    }
    di    = __builtin_amdgcn_readfirstlane(di);
    diff  = __builtin_amdgcn_readfirstlane(diff);
    combo = __builtin_amdgcn_readfirstlane(combo);
    q0    = __builtin_amdgcn_readfirstlane(q0);

    const int d = 1 << di;
    const int T = T0 - diff;
    const int Q = (T + d - 1) >> di;
    const int b = combo >> 5, h = combo & 31;
    const int ga = di * 2 + diff;

    const int* ip = idx + (ga * NH + h) * 8;
    int offs[8];
#pragma unroll
    for (int i = 0; i < 8; ++i)
        offs[i] = __builtin_amdgcn_readfirstlane((b * NC + ip[i]) * T0);

    F2 w2[36];
    load_w2(Wt + (ga * (NK * NH) + h * NK) * 9, w2);

#pragma unroll
    for (int k = 0; k < 16; ++k) accLDS[(k << 8) + tid] = 0.f;
    float* binsM = accLDS + tid;
    unsigned long long cnt = 0;

    const int t0 = r + q0 * d;
    float buf[10];
    {
        int u = t0 - 4 * d;
#pragma unroll
        for (int m = 0; m < 10; ++m) { buf[m] = gatherF(X, offs, u, T, diff); u += d; }
    }

    for (int outer = 0; outer < 6; ++outer) {
        if (q0 + outer * 10 >= Q) break;
        const int tb = t0 + outer * 10 * d;
#pragma unroll
        for (int ii = 0; ii < 10; ++ii) {
            const int t = tb + ii * d;
            F2 z2[4];
#pragma unroll
            for (int kp = 0; kp < 4; ++kp) z2[kp] = (F2){0.f, 0.f};
#pragma unroll
            for (int j = 0; j < 9; ++j) {
                float g = buf[(ii + j) % 10];
                F2 g2 = {g, g};
#pragma unroll
                for (int kp = 0; kp < 4; ++kp)
                    z2[kp] = __builtin_elementwise_fma(w2[j * 4 + kp], g2, z2[kp]);
            }
            float pz[8];
#pragma unroll
            for (int kp = 0; kp < 4; ++kp) {
                pz[2 * kp]     = packK(z2[kp].x, 2 * kp);
                pz[2 * kp + 1] = packK(z2[kp].y, 2 * kp + 1);
            }
            float best = max8(pz), worst = min8(pz);
            if (t < T) {
                int biK = __float_as_uint(best) & 7;
                int wiK = __float_as_uint(worst) & 7;
                atomicAdd(&binsM[biK << 8], best);   // no ds_read in loop -> safe
                cnt += 1ull << (wiK << 3);
            }
            buf[ii] = gatherF(X, offs, t + 6 * d, T, diff);
        }
    }

#pragma unroll
    for (int k = 0; k < 8; ++k)
        accLDS[((8 + k) << 8) + tid] = (float)((unsigned)(cnt >> (k * 8)) & 255u);

    block_reduce_out(accLDS, tid, ga, b, h, out);
}

__global__ void zeroK(float* __restrict__ out, int n) {
    int i = blockIdx.x * 256 + threadIdx.x;
    if (i < n) out[i] = 0.f;
}

extern "C" void kernel_launch(void* const* d_in, const int* in_sizes, int n_in,
                              void* d_out, int out_size, void* d_ws, size_t ws_size,
                              hipStream_t stream) {
    const float* X  = (const float*)d_in[0];
    const float* Wt = (const float*)d_in[1];
    const int*  idx = (const int*)d_in[2];
    float* out = (float*)d_out;

    zeroK<<<(out_size + 255) / 256, 256, 0, stream>>>(out, out_size);
    kernA<<<A_TOTAL_BLOCKS, 256, 0, stream>>>(X, Wt, idx, out);
    kernB<<<B_BLOCKS, 256, 0, stream>>>(X, Wt, idx, out);
}